// Round 1
// baseline (1431.474 us; speedup 1.0000x reference)
//
#include <hip/hip_runtime.h>

typedef __bf16 bf16_t;
typedef bf16_t bf16x8 __attribute__((ext_vector_type(8)));
typedef float  floatx4 __attribute__((ext_vector_type(4)));
typedef unsigned short u16;
typedef unsigned long long u64;

#define DEV __device__ __forceinline__

static constexpr int B_  = 256;
static constexpr int T_  = 64;
static constexpr int H_  = 512;
static constexpr int G_  = 2048;   // 4*H
static constexpr int INS = 500;
static constexpr int NDP = 16640;  // padded OUT_DIM
static constexpr int NDR = 16532;  // real OUT_DIM

DEV u16 f2bf(float f) {
  unsigned u = __builtin_bit_cast(unsigned, f);
  u += 0x7FFFu + ((u >> 16) & 1u);
  return (u16)(u >> 16);
}
DEV float bf2f(u16 h) {
  unsigned u = ((unsigned)h) << 16;
  return __builtin_bit_cast(float, u);
}
DEV float sigm(float x)  { return 1.f / (1.f + __expf(-x)); }
DEV float tanh_(float x) { return 1.f - 2.f / (__expf(2.f * x) + 1.f); }

// ---------------------------------------------------------------- prep kernels
__global__ void prep_weights_kernel(
    const float* __restrict__ w_ih0, const float* __restrict__ w_hh0,
    const float* __restrict__ b_ih0, const float* __restrict__ b_hh0,
    const float* __restrict__ w_ih1, const float* __restrict__ w_hh1,
    const float* __restrict__ b_ih1, const float* __restrict__ b_hh1,
    const float* __restrict__ fc_w,  const float* __restrict__ fc_b,
    u16* __restrict__ wih0b, u16* __restrict__ whh0b,
    u16* __restrict__ w1b,   u16* __restrict__ fcwb,
    float* __restrict__ bias0p, float* __restrict__ bias1p,
    float* __restrict__ fcbp)
{
  const int gsz = gridDim.x * blockDim.x;
  const int g0  = blockIdx.x * blockDim.x + threadIdx.x;
  // permuted gate order: p = (j>>4)*64 + (j&15)*4 + g  (j = hidden, g = i/f/g/o)
  for (int i = g0; i < 2048 * 512; i += gsz) {
    int pp = i >> 9, k = i & 511;
    int s = pp >> 6, rr = pp & 63, jj = rr >> 2, g = rr & 3;
    int srow = g * 512 + s * 16 + jj;
    wih0b[i] = f2bf(k < INS ? w_ih0[(size_t)srow * INS + k] : 0.f);
    whh0b[i] = f2bf(w_hh0[(size_t)srow * 512 + k]);
  }
  for (int i = g0; i < 2048 * 1024; i += gsz) {
    int pp = i >> 10, k = i & 1023;
    int s = pp >> 6, rr = pp & 63, jj = rr >> 2, g = rr & 3;
    int srow = g * 512 + s * 16 + jj;
    float v = (k < 512) ? w_ih1[(size_t)srow * 512 + k]
                        : w_hh1[(size_t)srow * 512 + (k - 512)];
    w1b[i] = f2bf(v);
  }
  for (int i = g0; i < NDP * 512; i += gsz) {
    int n = i >> 9, k = i & 511;
    fcwb[i] = f2bf(n < NDR ? fc_w[(size_t)n * 512 + k] : 0.f);
  }
  for (int i = g0; i < 2048; i += gsz) {
    int s = i >> 6, rr = i & 63, jj = rr >> 2, g = rr & 3;
    int srow = g * 512 + s * 16 + jj;
    bias0p[i] = b_ih0[srow] + b_hh0[srow];
    bias1p[i] = b_ih1[srow] + b_hh1[srow];
  }
  for (int i = g0; i < NDP; i += gsz) fcbp[i] = (i < NDR) ? fc_b[i] : 0.f;
}

__global__ void prep_x_kernel(const float* __restrict__ x, u16* __restrict__ xb) {
  const int gsz = gridDim.x * blockDim.x;
  for (int i = blockIdx.x * blockDim.x + threadIdx.x; i < T_ * B_ * 512; i += gsz) {
    int k = i & 511;
    int b = (i >> 9) & 255;
    int t = i >> 17;
    float v = (k < INS) ? x[((size_t)b * T_ + t) * INS + k] : 0.f;
    xb[i] = f2bf(v);
  }
}

__global__ void prep_sigma_kernel(const float* __restrict__ raw,
                                  u16* __restrict__ Gb, u16* __restrict__ Ldb,
                                  float* __restrict__ idio)
{
  const int gsz = gridDim.x * blockDim.x;
  const int g0  = blockIdx.x * blockDim.x + threadIdx.x;
  for (int i = g0; i < 256 * 512 * 32; i += gsz) {
    int b = i >> 14, rr = i & 16383, n = rr >> 5, f = rr & 31;
    const float* rb = raw + (size_t)b * NDP;
    float ld = (n < 500) ? rb[n * 32 + f] : 0.f;
    float fv = __expf(rb[16000 + f]);
    Ldb[i] = f2bf(ld);
    Gb[i]  = f2bf(ld * fv);
  }
  for (int i = g0; i < 256 * 512; i += gsz) {
    int b = i >> 9, a = i & 511;
    if (a < 500) idio[(size_t)b * 500 + a] = __expf(raw[(size_t)b * NDP + 16032 + a]);
  }
}

// ---------------------------------------------------------------- GEMM: C[M][N] = A[M][K] @ Bw[N][K]^T + bias
template <int OUT_BF16>
__global__ __launch_bounds__(256) void gemm_bt(
    const u16* __restrict__ A, const u16* __restrict__ Bw,
    const float* __restrict__ bias, void* __restrict__ C,
    int M, int N, int K)
{
  __shared__ alignas(16) u16 As[128 * 32];
  __shared__ alignas(16) u16 Bs[128 * 32];
  const int tid = threadIdx.x;
  const int wave = tid >> 6, lane = tid & 63;
  const int m0 = blockIdx.y * 128, n0 = blockIdx.x * 128;
  const int wr = wave >> 1, wc = wave & 1;

  floatx4 zero = {0.f, 0.f, 0.f, 0.f};
  floatx4 acc[4][4];
#pragma unroll
  for (int i = 0; i < 4; i++)
#pragma unroll
    for (int j = 0; j < 4; j++) acc[i][j] = zero;

  uint4 ra[2], rb[2];
#pragma unroll
  for (int i = 0; i < 2; i++) {
    int idx = tid + (i << 8);
    int row = idx >> 2, ks = idx & 3;
    ra[i] = *(const uint4*)(A  + (size_t)(m0 + row) * K + ks * 8);
    rb[i] = *(const uint4*)(Bw + (size_t)(n0 + row) * K + ks * 8);
  }

  for (int kc = 0; kc < K; kc += 32) {
    __syncthreads();
#pragma unroll
    for (int i = 0; i < 2; i++) {
      int idx = tid + (i << 8);
      int row = idx >> 2, ks = idx & 3;
      int off = row * 32 + ((ks ^ (row & 3)) << 3);   // XOR swizzle vs bank conflicts
      *(uint4*)(As + off) = ra[i];
      *(uint4*)(Bs + off) = rb[i];
    }
    __syncthreads();
    if (kc + 32 < K) {
#pragma unroll
      for (int i = 0; i < 2; i++) {
        int idx = tid + (i << 8);
        int row = idx >> 2, ks = idx & 3;
        ra[i] = *(const uint4*)(A  + (size_t)(m0 + row) * K + kc + 32 + ks * 8);
        rb[i] = *(const uint4*)(Bw + (size_t)(n0 + row) * K + kc + 32 + ks * 8);
      }
    }
    const int kg = lane >> 4;
    bf16x8 af[4], bfr[4];
#pragma unroll
    for (int i = 0; i < 4; i++) {
      int rowa = wr * 64 + i * 16 + (lane & 15);
      af[i] = *(const bf16x8*)(As + rowa * 32 + ((kg ^ (rowa & 3)) << 3));
      int rowb = wc * 64 + i * 16 + (lane & 15);
      bfr[i] = *(const bf16x8*)(Bs + rowb * 32 + ((kg ^ (rowb & 3)) << 3));
    }
#pragma unroll
    for (int i = 0; i < 4; i++)
#pragma unroll
      for (int j = 0; j < 4; j++)
        acc[i][j] = __builtin_amdgcn_mfma_f32_16x16x32_bf16(af[i], bfr[j], acc[i][j], 0, 0, 0);
  }

  const int r0 = (lane >> 4) * 4, cl = lane & 15;
#pragma unroll
  for (int j = 0; j < 4; j++) {
    int col = n0 + wc * 64 + j * 16 + cl;
    float bv = bias[col];
#pragma unroll
    for (int i = 0; i < 4; i++) {
      int row = m0 + wr * 64 + i * 16 + r0;
#pragma unroll
      for (int r = 0; r < 4; r++) {
        float v = acc[i][j][r] + bv;
        if (OUT_BF16) ((u16*)C)[(size_t)(row + r) * N + col] = f2bf(v);
        else          ((float*)C)[(size_t)(row + r) * N + col] = v;
      }
    }
  }
}

// ---------------------------------------------------------------- Fused 2-layer LSTM
// 512 blocks: bm=blockIdx>>5 (16 batch groups of 16), bn=blockIdx&31 (32 gate slices).
// Pipelined: iteration t computes h0(t) = f(h0(t-1)) AND h1(t-1) = f(h0(t-1), h1(t-2)),
// both from the state published by barrier t-1 -> ONE barrier per iteration instead
// of two (one per layer-kernel).  65 iterations total (t=64 drains h1(63)).
// Per-block weights: W_hh0 slice (64 regs) + W1 slice (128 regs) -> AGPR-resident;
// __launch_bounds__(256,2) forces combined <=256 regs so all 512 blocks stay
// co-resident (2/CU) — required for the barrier to make progress.
// Cross-block h + barrier use agent-scope RELAXED atomics only (coherence point);
// compiler drains vmcnt(0) before s_barrier, so all waves' h-stores are ack'd
// before lane 0 increments the counter.
__global__ __launch_bounds__(256, 2) void lstm_fused_kernel(
    const u16* __restrict__ xg,     // [64][256][2048] bf16, permuted gate order
    const u16* __restrict__ whh0,   // [2048][512]  bf16, permuted rows
    const u16* __restrict__ w1,     // [2048][1024] bf16, permuted rows, cols = [w_ih1 | w_hh1]
    const float* __restrict__ bias1p,
    u16* __restrict__ hp0,          // [2][256][512] ping-pong for h0
    u16* __restrict__ hp1,          // [2][256][512] ping-pong for h1; h1(63) ends in slot 1
    unsigned* __restrict__ bars)    // [16][32]
{
  const int tid = threadIdx.x;
  const int wave = tid >> 6, lane = tid & 63;
  const int bm = blockIdx.x >> 5;
  const int bn = blockIdx.x & 31;
  const int bbase = bm << 4;
  const int pbase = bn << 6;

  __shared__ alignas(16) u16 h_lds[2 * 16 * 512];       // [0]=h0(t-1), [1]=h1(t-2)
  __shared__ alignas(16) float gates0_lds[16 * 68];     // pad 64->68: no 4-way conflict
  __shared__ alignas(16) float gates1_lds[16 * 68];

  bf16x8 wf0[16];
  bf16x8 wf1[32];
  {
    const u16* wp = whh0 + (size_t)(pbase + wave * 16 + (lane & 15)) * 512 + (lane >> 4) * 8;
#pragma unroll
    for (int kc = 0; kc < 16; kc++) wf0[kc] = *(const bf16x8*)(wp + kc * 32);
    const u16* wq = w1 + (size_t)(pbase + wave * 16 + (lane & 15)) * 1024 + (lane >> 4) * 8;
#pragma unroll
    for (int kc = 0; kc < 32; kc++) wf1[kc] = *(const bf16x8*)(wq + kc * 32);
  }

  const int qb = tid >> 4, qj = tid & 15;
  const float4 bq = *(const float4*)(bias1p + pbase + qj * 4);
  float c0 = 0.f, c1 = 0.f;
  unsigned target = 0;
  unsigned* mybar = bars + bm * 32;
  const floatx4 zero = {0.f, 0.f, 0.f, 0.f};
  const size_t hoff = (size_t)(bbase + qb) * H_ + (bn << 4) + qj;

#pragma unroll 1
  for (int t = 0; t <= 64; t++) {
    // ---- Phase A: load h0(t-1) [slot (t-1)&1] and h1(t-2) [slot t&1] into LDS
    {
      const u64* s0 = (const u64*)(hp0 + (size_t)((t + 1) & 1) * (B_ * H_) + (size_t)bbase * H_);
      const u64* s1 = (const u64*)(hp1 + (size_t)(t & 1) * (B_ * H_) + (size_t)bbase * H_);
#pragma unroll
      for (int i = 0; i < 4; i++) {
        int idx = tid + (i << 8);
        int b = idx >> 6, kg = idx & 63;
        int dst = b * 512 + ((kg ^ (b & 7)) << 3);
        u64 a0 = __hip_atomic_load(s0 + idx * 2,     __ATOMIC_RELAXED, __HIP_MEMORY_SCOPE_AGENT);
        u64 a1 = __hip_atomic_load(s0 + idx * 2 + 1, __ATOMIC_RELAXED, __HIP_MEMORY_SCOPE_AGENT);
        u64 b0 = __hip_atomic_load(s1 + idx * 2,     __ATOMIC_RELAXED, __HIP_MEMORY_SCOPE_AGENT);
        u64 b1 = __hip_atomic_load(s1 + idx * 2 + 1, __ATOMIC_RELAXED, __HIP_MEMORY_SCOPE_AGENT);
        *(u64*)(h_lds + dst)            = a0;
        *(u64*)(h_lds + dst + 4)        = a1;
        *(u64*)(h_lds + 8192 + dst)     = b0;
        *(u64*)(h_lds + 8192 + dst + 4) = b1;
      }
    }
    // prefetch xg(t) early so its latency hides under the MFMA phase
    ushort4 xr = {0, 0, 0, 0};
    if (t < 64)
      xr = *(const ushort4*)(xg + ((size_t)t * B_ + bbase + qb) * G_ + pbase + qj * 4);
    __syncthreads();

    // ---- Phase B: MFMAs.  First 16 K-groups: A-fragment (h0(t-1)) shared by both layers.
    floatx4 acc0 = zero, acc1 = zero;
    {
      const int b = lane & 15, qd = lane >> 4;
#pragma unroll
      for (int kc = 0; kc < 16; kc++) {
        int kgrp = kc * 4 + qd;
        bf16x8 a = *(const bf16x8*)(h_lds + b * 512 + ((kgrp ^ (b & 7)) << 3));
        acc0 = __builtin_amdgcn_mfma_f32_16x16x32_bf16(a, wf0[kc], acc0, 0, 0, 0);
        acc1 = __builtin_amdgcn_mfma_f32_16x16x32_bf16(a, wf1[kc], acc1, 0, 0, 0);
      }
#pragma unroll
      for (int kc = 0; kc < 16; kc++) {
        int kgrp = kc * 4 + qd;
        bf16x8 a = *(const bf16x8*)(h_lds + 8192 + b * 512 + ((kgrp ^ (b & 7)) << 3));
        acc1 = __builtin_amdgcn_mfma_f32_16x16x32_bf16(a, wf1[16 + kc], acc1, 0, 0, 0);
      }
    }
    // ---- Phase C: gate tiles -> LDS transpose
    {
      int r0 = (lane >> 4) * 4, cc = wave * 16 + (lane & 15);
#pragma unroll
      for (int r = 0; r < 4; r++) {
        gates0_lds[(r0 + r) * 68 + cc] = acc0[r];
        gates1_lds[(r0 + r) * 68 + cc] = acc1[r];
      }
    }
    __syncthreads();

    // ---- Phase D: elementwise + agent-scope h stores
    if (t < 64) {                        // layer 0 produces h0(t) -> slot t&1
      const float4 gm = *(const float4*)(gates0_lds + qb * 68 + qj * 4);
      float gi = gm.x + bf2f(xr.x);
      float gf = gm.y + bf2f(xr.y);
      float gg = gm.z + bf2f(xr.z);
      float go = gm.w + bf2f(xr.w);
      c0 = sigm(gf) * c0 + sigm(gi) * tanh_(gg);
      float h = sigm(go) * tanh_(c0);
      __hip_atomic_store(hp0 + (size_t)(t & 1) * (B_ * H_) + hoff, f2bf(h),
                         __ATOMIC_RELAXED, __HIP_MEMORY_SCOPE_AGENT);
    }
    if (t >= 1) {                        // layer 1 produces h1(t-1) -> slot (t-1)&1
      const float4 gm = *(const float4*)(gates1_lds + qb * 68 + qj * 4);
      float gi = gm.x + bq.x;
      float gf = gm.y + bq.y;
      float gg = gm.z + bq.z;
      float go = gm.w + bq.w;
      c1 = sigm(gf) * c1 + sigm(gi) * tanh_(gg);
      float h = sigm(go) * tanh_(c1);
      __hip_atomic_store(hp1 + (size_t)((t + 1) & 1) * (B_ * H_) + hoff, f2bf(h),
                         __ATOMIC_RELAXED, __HIP_MEMORY_SCOPE_AGENT);
    }

    // ---- Phase E: inter-block barrier (one per iteration for BOTH layers)
    target += 32;
    if (t < 64) {
      __syncthreads();   // drains vmcnt(0) for ALL waves' h stores
      if (tid == 0) {
        __hip_atomic_fetch_add(mybar, 1u, __ATOMIC_RELAXED, __HIP_MEMORY_SCOPE_AGENT);
        while (__hip_atomic_load(mybar, __ATOMIC_RELAXED, __HIP_MEMORY_SCOPE_AGENT) < target)
          __builtin_amdgcn_s_sleep(2);
      }
      __syncthreads();
    }
  }
}

// ---------------------------------------------------------------- Sigma: out[b] = G_b @ Ld_b^T + diag(idio)
__global__ __launch_bounds__(256) void sigma_kernel(
    const u16* __restrict__ Gb, const u16* __restrict__ Ldb,
    const float* __restrict__ idio, float* __restrict__ out)
{
  const int bz = blockIdx.z;
  const int n0 = blockIdx.y * 128;
  const int m0 = blockIdx.x * 128;
  __shared__ alignas(16) u16 As[128 * 32];
  __shared__ alignas(16) u16 Bs[128 * 32];
  const int tid = threadIdx.x, wave = tid >> 6, lane = tid & 63;
  const int wr = wave >> 1, wc = wave & 1;

  const u16* ga = Gb  + (size_t)bz * (512 * 32) + n0 * 32;
  const u16* gb = Ldb + (size_t)bz * (512 * 32) + m0 * 32;
#pragma unroll
  for (int i = 0; i < 2; i++) {
    int idx = tid + (i << 8);
    int row = idx >> 2, ks = idx & 3;
    int off = row * 32 + ((ks ^ (row & 3)) << 3);
    *(uint4*)(As + off) = *(const uint4*)(ga + idx * 8);
    *(uint4*)(Bs + off) = *(const uint4*)(gb + idx * 8);
  }
  __syncthreads();

  const int kg = lane >> 4;
  bf16x8 af[4], bfr[4];
#pragma unroll
  for (int i = 0; i < 4; i++) {
    int rowa = wr * 64 + i * 16 + (lane & 15);
    af[i] = *(const bf16x8*)(As + rowa * 32 + ((kg ^ (rowa & 3)) << 3));
    int rowb = wc * 64 + i * 16 + (lane & 15);
    bfr[i] = *(const bf16x8*)(Bs + rowb * 32 + ((kg ^ (rowb & 3)) << 3));
  }
  floatx4 zero = {0.f, 0.f, 0.f, 0.f};
  floatx4 acc[4][4];
#pragma unroll
  for (int i = 0; i < 4; i++)
#pragma unroll
    for (int j = 0; j < 4; j++)
      acc[i][j] = __builtin_amdgcn_mfma_f32_16x16x32_bf16(af[i], bfr[j], zero, 0, 0, 0);

  const int r0 = (lane >> 4) * 4, cl = lane & 15;
  float* ob = out + (size_t)bz * 250000;
#pragma unroll
  for (int j = 0; j < 4; j++) {
    int col = m0 + wc * 64 + j * 16 + cl;
#pragma unroll
    for (int i = 0; i < 4; i++) {
      int row = n0 + wr * 64 + i * 16 + r0;
#pragma unroll
      for (int r = 0; r < 4; r++) {
        int rr = row + r;
        if (rr < 500 && col < 500) {
          float v = acc[i][j][r];
          if (rr == col) v += idio[(size_t)bz * 500 + rr];
          ob[(size_t)rr * 500 + col] = v;
        }
      }
    }
  }
}

// ---------------------------------------------------------------- launcher
extern "C" void kernel_launch(void* const* d_in, const int* in_sizes, int n_in,
                              void* d_out, int out_size, void* d_ws, size_t ws_size,
                              hipStream_t stream)
{
  const float* x     = (const float*)d_in[0];
  const float* w_ih0 = (const float*)d_in[1];
  const float* w_hh0 = (const float*)d_in[2];
  const float* b_ih0 = (const float*)d_in[3];
  const float* b_hh0 = (const float*)d_in[4];
  const float* w_ih1 = (const float*)d_in[5];
  const float* w_hh1 = (const float*)d_in[6];
  const float* b_ih1 = (const float*)d_in[7];
  const float* b_hh1 = (const float*)d_in[8];
  const float* fc_w  = (const float*)d_in[9];
  const float* fc_b  = (const float*)d_in[10];
  float* out = (float*)d_out;

  char* p = (char*)d_ws;
  auto alloc = [&](size_t n) { char* r = p; p += (n + 255) & ~(size_t)255; return r; };

  u16*  xb     = (u16*)alloc((size_t)T_ * B_ * 512 * 2);
  u16*  wih0b  = (u16*)alloc((size_t)2048 * 512 * 2);
  u16*  whh0b  = (u16*)alloc((size_t)2048 * 512 * 2);
  u16*  w1b    = (u16*)alloc((size_t)2048 * 1024 * 2);
  u16*  fcwb   = (u16*)alloc((size_t)NDP * 512 * 2);
  float* bias0p = (float*)alloc(2048 * 4);
  float* bias1p = (float*)alloc(2048 * 4);
  float* fcbp   = (float*)alloc((size_t)NDP * 4);
  u16*  xg0    = (u16*)alloc((size_t)T_ * B_ * G_ * 2);
  u16*  hp0    = (u16*)alloc((size_t)2 * B_ * H_ * 2);
  u16*  hp1    = (u16*)alloc((size_t)2 * B_ * H_ * 2);
  float* raw    = (float*)alloc((size_t)B_ * NDP * 4);
  u16*  Gbuf   = (u16*)alloc((size_t)256 * 512 * 32 * 2);
  u16*  Ldbuf  = (u16*)alloc((size_t)256 * 512 * 32 * 2);
  float* idio   = (float*)alloc((size_t)256 * 512 * 4);
  unsigned* bars0 = (unsigned*)alloc(16 * 32 * 4);

  hipMemsetAsync(hp0, 0, (size_t)2 * B_ * H_ * 2, stream);
  hipMemsetAsync(hp1, 0, (size_t)2 * B_ * H_ * 2, stream);
  hipMemsetAsync(bars0, 0, 16 * 32 * 4, stream);

  dim3 blk(256);
  prep_weights_kernel<<<512, blk, 0, stream>>>(w_ih0, w_hh0, b_ih0, b_hh0,
                                               w_ih1, w_hh1, b_ih1, b_hh1,
                                               fc_w, fc_b,
                                               wih0b, whh0b, w1b, fcwb,
                                               bias0p, bias1p, fcbp);
  prep_x_kernel<<<1024, blk, 0, stream>>>(x, xb);

  // xg0 = xb @ wih0b^T + (b_ih0 + b_hh0)   [16384 x 2048 x 512]
  gemm_bt<1><<<dim3(G_ / 128, (T_ * B_) / 128), blk, 0, stream>>>(
      xb, wih0b, bias0p, xg0, T_ * B_, G_, 512);

  // fused two-layer LSTM; final h1(63) lands in hp1 slot 1
  lstm_fused_kernel<<<512, blk, 0, stream>>>(xg0, whh0b, w1b, bias1p, hp0, hp1, bars0);

  // raw = h1_final @ fcwb^T + fc_b  [256 x 16640 x 512]
  gemm_bt<0><<<dim3(NDP / 128, B_ / 128), blk, 0, stream>>>(
      hp1 + (size_t)B_ * H_, fcwb, fcbp, raw, B_, NDP, 512);

  prep_sigma_kernel<<<1024, blk, 0, stream>>>(raw, Gbuf, Ldbuf, idio);
  sigma_kernel<<<dim3(4, 4, 256), blk, 0, stream>>>(Gbuf, Ldbuf, idio, out);
}

// Round 2
// 1015.593 us; speedup vs baseline: 1.4095x; 1.4095x over previous
//
#include <hip/hip_runtime.h>

typedef __bf16 bf16_t;
typedef bf16_t bf16x8 __attribute__((ext_vector_type(8)));
typedef float  floatx4 __attribute__((ext_vector_type(4)));
typedef unsigned short u16;
typedef unsigned long long u64;

#define DEV __device__ __forceinline__

static constexpr int B_  = 256;
static constexpr int T_  = 64;
static constexpr int H_  = 512;
static constexpr int G_  = 2048;   // 4*H
static constexpr int INS = 500;
static constexpr int NDP = 16640;  // padded OUT_DIM
static constexpr int NDR = 16532;  // real OUT_DIM

DEV u16 f2bf(float f) {
  unsigned u = __builtin_bit_cast(unsigned, f);
  u += 0x7FFFu + ((u >> 16) & 1u);
  return (u16)(u >> 16);
}
DEV float bf2f(u16 h) {
  unsigned u = ((unsigned)h) << 16;
  return __builtin_bit_cast(float, u);
}
DEV float sigm(float x)  { return 1.f / (1.f + __expf(-x)); }
DEV float tanh_(float x) { return 1.f - 2.f / (__expf(2.f * x) + 1.f); }

// ---------------------------------------------------------------- prep kernels
__global__ void prep_weights_kernel(
    const float* __restrict__ w_ih0, const float* __restrict__ w_hh0,
    const float* __restrict__ b_ih0, const float* __restrict__ b_hh0,
    const float* __restrict__ w_ih1, const float* __restrict__ w_hh1,
    const float* __restrict__ b_ih1, const float* __restrict__ b_hh1,
    const float* __restrict__ fc_w,  const float* __restrict__ fc_b,
    u16* __restrict__ wih0b, u16* __restrict__ whh0b,
    u16* __restrict__ w1b,   u16* __restrict__ fcwb,
    float* __restrict__ bias0p, float* __restrict__ bias1p,
    float* __restrict__ fcbp)
{
  const int gsz = gridDim.x * blockDim.x;
  const int g0  = blockIdx.x * blockDim.x + threadIdx.x;
  // permuted gate order: p = (j>>4)*64 + (j&15)*4 + g  (j = hidden, g = i/f/g/o)
  for (int i = g0; i < 2048 * 512; i += gsz) {
    int pp = i >> 9, k = i & 511;
    int s = pp >> 6, rr = pp & 63, jj = rr >> 2, g = rr & 3;
    int srow = g * 512 + s * 16 + jj;
    wih0b[i] = f2bf(k < INS ? w_ih0[(size_t)srow * INS + k] : 0.f);
    whh0b[i] = f2bf(w_hh0[(size_t)srow * 512 + k]);
  }
  for (int i = g0; i < 2048 * 1024; i += gsz) {
    int pp = i >> 10, k = i & 1023;
    int s = pp >> 6, rr = pp & 63, jj = rr >> 2, g = rr & 3;
    int srow = g * 512 + s * 16 + jj;
    float v = (k < 512) ? w_ih1[(size_t)srow * 512 + k]
                        : w_hh1[(size_t)srow * 512 + (k - 512)];
    w1b[i] = f2bf(v);
  }
  for (int i = g0; i < NDP * 512; i += gsz) {
    int n = i >> 9, k = i & 511;
    fcwb[i] = f2bf(n < NDR ? fc_w[(size_t)n * 512 + k] : 0.f);
  }
  for (int i = g0; i < 2048; i += gsz) {
    int s = i >> 6, rr = i & 63, jj = rr >> 2, g = rr & 3;
    int srow = g * 512 + s * 16 + jj;
    bias0p[i] = b_ih0[srow] + b_hh0[srow];
    bias1p[i] = b_ih1[srow] + b_hh1[srow];
  }
  for (int i = g0; i < NDP; i += gsz) fcbp[i] = (i < NDR) ? fc_b[i] : 0.f;
}

__global__ void prep_x_kernel(const float* __restrict__ x, u16* __restrict__ xb) {
  const int gsz = gridDim.x * blockDim.x;
  for (int i = blockIdx.x * blockDim.x + threadIdx.x; i < T_ * B_ * 512; i += gsz) {
    int k = i & 511;
    int b = (i >> 9) & 255;
    int t = i >> 17;
    float v = (k < INS) ? x[((size_t)b * T_ + t) * INS + k] : 0.f;
    xb[i] = f2bf(v);
  }
}

__global__ void prep_sigma_kernel(const float* __restrict__ raw,
                                  u16* __restrict__ Gb, u16* __restrict__ Ldb,
                                  float* __restrict__ idio)
{
  const int gsz = gridDim.x * blockDim.x;
  const int g0  = blockIdx.x * blockDim.x + threadIdx.x;
  for (int i = g0; i < 256 * 512 * 32; i += gsz) {
    int b = i >> 14, rr = i & 16383, n = rr >> 5, f = rr & 31;
    const float* rb = raw + (size_t)b * NDP;
    float ld = (n < 500) ? rb[n * 32 + f] : 0.f;
    float fv = __expf(rb[16000 + f]);
    Ldb[i] = f2bf(ld);
    Gb[i]  = f2bf(ld * fv);
  }
  for (int i = g0; i < 256 * 512; i += gsz) {
    int b = i >> 9, a = i & 511;
    if (a < 500) idio[(size_t)b * 500 + a] = __expf(raw[(size_t)b * NDP + 16032 + a]);
  }
}

// ---------------------------------------------------------------- GEMM: C[M][N] = A[M][K] @ Bw[N][K]^T + bias
template <int OUT_BF16>
__global__ __launch_bounds__(256) void gemm_bt(
    const u16* __restrict__ A, const u16* __restrict__ Bw,
    const float* __restrict__ bias, void* __restrict__ C,
    int M, int N, int K)
{
  __shared__ alignas(16) u16 As[128 * 32];
  __shared__ alignas(16) u16 Bs[128 * 32];
  const int tid = threadIdx.x;
  const int wave = tid >> 6, lane = tid & 63;
  const int m0 = blockIdx.y * 128, n0 = blockIdx.x * 128;
  const int wr = wave >> 1, wc = wave & 1;

  floatx4 zero = {0.f, 0.f, 0.f, 0.f};
  floatx4 acc[4][4];
#pragma unroll
  for (int i = 0; i < 4; i++)
#pragma unroll
    for (int j = 0; j < 4; j++) acc[i][j] = zero;

  uint4 ra[2], rb[2];
#pragma unroll
  for (int i = 0; i < 2; i++) {
    int idx = tid + (i << 8);
    int row = idx >> 2, ks = idx & 3;
    ra[i] = *(const uint4*)(A  + (size_t)(m0 + row) * K + ks * 8);
    rb[i] = *(const uint4*)(Bw + (size_t)(n0 + row) * K + ks * 8);
  }

  for (int kc = 0; kc < K; kc += 32) {
    __syncthreads();
#pragma unroll
    for (int i = 0; i < 2; i++) {
      int idx = tid + (i << 8);
      int row = idx >> 2, ks = idx & 3;
      int off = row * 32 + ((ks ^ (row & 3)) << 3);   // XOR swizzle vs bank conflicts
      *(uint4*)(As + off) = ra[i];
      *(uint4*)(Bs + off) = rb[i];
    }
    __syncthreads();
    if (kc + 32 < K) {
#pragma unroll
      for (int i = 0; i < 2; i++) {
        int idx = tid + (i << 8);
        int row = idx >> 2, ks = idx & 3;
        ra[i] = *(const uint4*)(A  + (size_t)(m0 + row) * K + kc + 32 + ks * 8);
        rb[i] = *(const uint4*)(Bw + (size_t)(n0 + row) * K + kc + 32 + ks * 8);
      }
    }
    const int kg = lane >> 4;
    bf16x8 af[4], bfr[4];
#pragma unroll
    for (int i = 0; i < 4; i++) {
      int rowa = wr * 64 + i * 16 + (lane & 15);
      af[i] = *(const bf16x8*)(As + rowa * 32 + ((kg ^ (rowa & 3)) << 3));
      int rowb = wc * 64 + i * 16 + (lane & 15);
      bfr[i] = *(const bf16x8*)(Bs + rowb * 32 + ((kg ^ (rowb & 3)) << 3));
    }
#pragma unroll
    for (int i = 0; i < 4; i++)
#pragma unroll
      for (int j = 0; j < 4; j++)
        acc[i][j] = __builtin_amdgcn_mfma_f32_16x16x32_bf16(af[i], bfr[j], acc[i][j], 0, 0, 0);
  }

  const int r0 = (lane >> 4) * 4, cl = lane & 15;
#pragma unroll
  for (int j = 0; j < 4; j++) {
    int col = n0 + wc * 64 + j * 16 + cl;
    float bv = bias[col];
#pragma unroll
    for (int i = 0; i < 4; i++) {
      int row = m0 + wr * 64 + i * 16 + r0;
#pragma unroll
      for (int r = 0; r < 4; r++) {
        float v = acc[i][j][r] + bv;
        if (OUT_BF16) ((u16*)C)[(size_t)(row + r) * N + col] = f2bf(v);
        else          ((float*)C)[(size_t)(row + r) * N + col] = v;
      }
    }
  }
}

// ---------------------------------------------------------------- Fused 2-layer LSTM, K-split
// 256 blocks x 512 threads: bm=blockIdx>>5 (8 batch groups of 32), bn=blockIdx&31
// (32 gate slices of 64 rows).  8 waves = 4 row-groups x 2 K-halves:
//   wave (rw,kh): rw = 16 gate rows, kh = K-half.  L0: kh splits K=512 into 256+256.
//   L1: kh=0 does w_ih1 x h0(t-1), kh=1 does w_hh1 x h1(t-2)  (natural 512/512 split).
// Weights/thread: (16 rows x 256 + 16 rows x 512) x 2B / 64 lanes = 96 regs -> no spill
// at the 256-reg cap (round-1's 192-reg version spilled: FETCH 534 MB of refetch).
// Partial K-sums combined through LDS gate buffer ALIASED onto the h staging buffer
// (dead after phase B).  LDS = 64 KB -> 1 block/CU, 256 blocks all resident.
// Inter-block barrier: store-flag + wave-parallel poll (no atomic-RMW serialization).
__global__ __launch_bounds__(512, 2) void lstm_fused_kernel(
    const u16* __restrict__ xg,     // [64][256][2048] bf16, permuted gate order (bias0 folded)
    const u16* __restrict__ whh0,   // [2048][512]  bf16, permuted rows
    const u16* __restrict__ w1,     // [2048][1024] bf16, permuted rows, cols [w_ih1 | w_hh1]
    const float* __restrict__ bias1p,
    u16* __restrict__ hp0,          // [2][256][512] ping-pong h0
    u16* __restrict__ hp1,          // [2][256][512] ping-pong h1; h1(63) ends in slot 1
    unsigned* __restrict__ bars)    // [8][32] timestep flags
{
  const int tid  = threadIdx.x;
  const int wv   = tid >> 6, lane = tid & 63;
  const int rw   = wv >> 1,  kh   = wv & 1;
  const int bl   = lane & 15, qd  = lane >> 4;
  const int bm   = blockIdx.x >> 5;
  const int bn   = blockIdx.x & 31;
  const int bbase = bm << 5;        // 32 batches
  const int pbase = bn << 6;        // 64 gate rows

  __shared__ alignas(16) u16 h_lds[2 * 32 * 512];   // 64 KB: [0]=h0(t-1), [1]=h1(t-2)
  float* gates = (float*)h_lds;     // aliased: [kh][layer][batch32][68] = 34816 B, written after phase B

  bf16x8 wf0[8], wf1[16];
  {
    const u16* wp = whh0 + (size_t)(pbase + rw * 16 + bl) * 512 + kh * 256 + qd * 8;
#pragma unroll
    for (int kc = 0; kc < 8; kc++)  wf0[kc] = *(const bf16x8*)(wp + kc * 32);
    const u16* wq = w1 + (size_t)(pbase + rw * 16 + bl) * 1024 + kh * 512 + qd * 8;
#pragma unroll
    for (int kc = 0; kc < 16; kc++) wf1[kc] = *(const bf16x8*)(wq + kc * 32);
  }

  const int eb = tid >> 4, ej = tid & 15;          // elementwise ownership: batch, hidden j
  const float4 bq = *(const float4*)(bias1p + pbase + ej * 4);
  float c0 = 0.f, c1 = 0.f;
  unsigned* grpbar = bars + bm * 32;
  const size_t hoff = (size_t)(bbase + eb) * H_ + (bn << 4) + ej;
  const floatx4 zero = {0.f, 0.f, 0.f, 0.f};

#pragma unroll 1
  for (int t = 0; t <= 64; t++) {
    // ---- Phase A: stage h0(t-1) [hp0 slot (t+1)&1] and h1(t-2) [hp1 slot t&1] into LDS
    {
      const u64* s0 = (const u64*)(hp0 + (size_t)((t + 1) & 1) * (B_ * H_));
      const u64* s1 = (const u64*)(hp1 + (size_t)(t & 1) * (B_ * H_));
#pragma unroll
      for (int i = 0; i < 4; i++) {
        int idx = tid + (i << 9);                  // 0..2047: 32 batches x 64 16B-units
        int bb = idx >> 6, u = idx & 63;
        size_t gp = ((size_t)(bbase + bb) * 64 + u) * 2;
        u64 a0 = __hip_atomic_load(s0 + gp,     __ATOMIC_RELAXED, __HIP_MEMORY_SCOPE_AGENT);
        u64 a1 = __hip_atomic_load(s0 + gp + 1, __ATOMIC_RELAXED, __HIP_MEMORY_SCOPE_AGENT);
        u64 b0 = __hip_atomic_load(s1 + gp,     __ATOMIC_RELAXED, __HIP_MEMORY_SCOPE_AGENT);
        u64 b1 = __hip_atomic_load(s1 + gp + 1, __ATOMIC_RELAXED, __HIP_MEMORY_SCOPE_AGENT);
        int dst = bb * 512 + ((u ^ (bb & 7)) << 3);
        *(u64*)(h_lds + dst)             = a0;
        *(u64*)(h_lds + dst + 4)         = a1;
        *(u64*)(h_lds + 16384 + dst)     = b0;
        *(u64*)(h_lds + 16384 + dst + 4) = b1;
      }
    }
    ushort4 xr = {0, 0, 0, 0};
    if (t < 64)
      xr = *(const ushort4*)(xg + ((size_t)t * B_ + bbase + eb) * G_ + pbase + ej * 4);
    __syncthreads();                               // (1) h_lds ready

    // ---- Phase B: MFMAs (partial K per wave)
    floatx4 acc0[2] = {zero, zero};
    floatx4 acc1[2] = {zero, zero};
    if (t < 64) {
#pragma unroll
      for (int kc = 0; kc < 8; kc++) {             // L0: this wave's K-half of h0
        int kg = kh * 32 + kc * 4 + qd;
        int sw = (kg ^ (bl & 7)) << 3;
        bf16x8 a0 = *(const bf16x8*)(h_lds + bl * 512 + sw);
        bf16x8 a1 = *(const bf16x8*)(h_lds + (16 + bl) * 512 + sw);
        acc0[0] = __builtin_amdgcn_mfma_f32_16x16x32_bf16(a0, wf0[kc], acc0[0], 0, 0, 0);
        acc0[1] = __builtin_amdgcn_mfma_f32_16x16x32_bf16(a1, wf0[kc], acc0[1], 0, 0, 0);
      }
    }
    {
      const u16* hb = h_lds + (kh ? 16384 : 0);    // L1 operand: kh=0 -> h0, kh=1 -> h1
#pragma unroll
      for (int kc = 0; kc < 16; kc++) {
        int kg = kc * 4 + qd;
        int sw = (kg ^ (bl & 7)) << 3;
        bf16x8 a0 = *(const bf16x8*)(hb + bl * 512 + sw);
        bf16x8 a1 = *(const bf16x8*)(hb + (16 + bl) * 512 + sw);
        acc1[0] = __builtin_amdgcn_mfma_f32_16x16x32_bf16(a0, wf1[kc], acc1[0], 0, 0, 0);
        acc1[1] = __builtin_amdgcn_mfma_f32_16x16x32_bf16(a1, wf1[kc], acc1[1], 0, 0, 0);
      }
    }
    __syncthreads();                               // (2) all LDS reads done before alias overwrite

    // ---- Phase C: write partial gate tiles into aliased gates buffer
    {
      const int rowc = rw * 16 + bl;
#pragma unroll
      for (int bt = 0; bt < 2; bt++)
#pragma unroll
        for (int r = 0; r < 4; r++) {
          int bat = bt * 16 + qd * 4 + r;
          gates[((kh * 2 + 0) * 32 + bat) * 68 + rowc] = acc0[bt][r];
          gates[((kh * 2 + 1) * 32 + bat) * 68 + rowc] = acc1[bt][r];
        }
    }
    __syncthreads();                               // (3) gates ready

    // ---- Phase D: combine K-halves, elementwise, agent-scope h stores
    if (t < 64) {                                  // layer 0 -> h0(t) -> hp0 slot t&1
      float4 ga = *(const float4*)(gates + ((0 * 2 + 0) * 32 + eb) * 68 + ej * 4);
      float4 gb = *(const float4*)(gates + ((1 * 2 + 0) * 32 + eb) * 68 + ej * 4);
      float gi = ga.x + gb.x + bf2f(xr.x);
      float gf = ga.y + gb.y + bf2f(xr.y);
      float gg = ga.z + gb.z + bf2f(xr.z);
      float go = ga.w + gb.w + bf2f(xr.w);
      c0 = sigm(gf) * c0 + sigm(gi) * tanh_(gg);
      float h = sigm(go) * tanh_(c0);
      __hip_atomic_store(hp0 + (size_t)(t & 1) * (B_ * H_) + hoff, f2bf(h),
                         __ATOMIC_RELAXED, __HIP_MEMORY_SCOPE_AGENT);
    }
    if (t >= 1) {                                  // layer 1 -> h1(t-1) -> hp1 slot (t+1)&1
      float4 ga = *(const float4*)(gates + ((0 * 2 + 1) * 32 + eb) * 68 + ej * 4);
      float4 gb = *(const float4*)(gates + ((1 * 2 + 1) * 32 + eb) * 68 + ej * 4);
      float gi = ga.x + gb.x + bq.x;
      float gf = ga.y + gb.y + bq.y;
      float gg = ga.z + gb.z + bq.z;
      float go = ga.w + gb.w + bq.w;
      c1 = sigm(gf) * c1 + sigm(gi) * tanh_(gg);
      float h = sigm(go) * tanh_(c1);
      __hip_atomic_store(hp1 + (size_t)((t + 1) & 1) * (B_ * H_) + hoff, f2bf(h),
                         __ATOMIC_RELAXED, __HIP_MEMORY_SCOPE_AGENT);
    }

    // ---- Phase E: inter-block barrier (store-flag + wave-parallel poll, no RMW)
    if (t < 64) {
      __syncthreads();                             // (4) drains vmcnt(0): all h stores ack'd
      if (tid == 0)
        __hip_atomic_store(grpbar + bn, (unsigned)(t + 1),
                           __ATOMIC_RELAXED, __HIP_MEMORY_SCOPE_AGENT);
      if (tid < 64) {
        const unsigned tgt = (unsigned)(t + 1);
        for (;;) {
          unsigned v = tgt;
          if (lane < 32)
            v = __hip_atomic_load(grpbar + lane, __ATOMIC_RELAXED, __HIP_MEMORY_SCOPE_AGENT);
          if (__all(v >= tgt)) break;
          __builtin_amdgcn_s_sleep(1);
        }
      }
      __syncthreads();                             // (5) release
    }
  }
}

// ---------------------------------------------------------------- Sigma: out[b] = G_b @ Ld_b^T + diag(idio)
__global__ __launch_bounds__(256) void sigma_kernel(
    const u16* __restrict__ Gb, const u16* __restrict__ Ldb,
    const float* __restrict__ idio, float* __restrict__ out)
{
  const int bz = blockIdx.z;
  const int n0 = blockIdx.y * 128;
  const int m0 = blockIdx.x * 128;
  __shared__ alignas(16) u16 As[128 * 32];
  __shared__ alignas(16) u16 Bs[128 * 32];
  const int tid = threadIdx.x, wave = tid >> 6, lane = tid & 63;
  const int wr = wave >> 1, wc = wave & 1;

  const u16* ga = Gb  + (size_t)bz * (512 * 32) + n0 * 32;
  const u16* gb = Ldb + (size_t)bz * (512 * 32) + m0 * 32;
#pragma unroll
  for (int i = 0; i < 2; i++) {
    int idx = tid + (i << 8);
    int row = idx >> 2, ks = idx & 3;
    int off = row * 32 + ((ks ^ (row & 3)) << 3);
    *(uint4*)(As + off) = *(const uint4*)(ga + idx * 8);
    *(uint4*)(Bs + off) = *(const uint4*)(gb + idx * 8);
  }
  __syncthreads();

  const int kg = lane >> 4;
  bf16x8 af[4], bfr[4];
#pragma unroll
  for (int i = 0; i < 4; i++) {
    int rowa = wr * 64 + i * 16 + (lane & 15);
    af[i] = *(const bf16x8*)(As + rowa * 32 + ((kg ^ (rowa & 3)) << 3));
    int rowb = wc * 64 + i * 16 + (lane & 15);
    bfr[i] = *(const bf16x8*)(Bs + rowb * 32 + ((kg ^ (rowb & 3)) << 3));
  }
  floatx4 zero = {0.f, 0.f, 0.f, 0.f};
  floatx4 acc[4][4];
#pragma unroll
  for (int i = 0; i < 4; i++)
#pragma unroll
    for (int j = 0; j < 4; j++)
      acc[i][j] = __builtin_amdgcn_mfma_f32_16x16x32_bf16(af[i], bfr[j], zero, 0, 0, 0);

  const int r0 = (lane >> 4) * 4, cl = lane & 15;
  float* ob = out + (size_t)bz * 250000;
#pragma unroll
  for (int j = 0; j < 4; j++) {
    int col = m0 + wc * 64 + j * 16 + cl;
#pragma unroll
    for (int i = 0; i < 4; i++) {
      int row = n0 + wr * 64 + i * 16 + r0;
#pragma unroll
      for (int r = 0; r < 4; r++) {
        int rr = row + r;
        if (rr < 500 && col < 500) {
          float v = acc[i][j][r];
          if (rr == col) v += idio[(size_t)bz * 500 + rr];
          ob[(size_t)rr * 500 + col] = v;
        }
      }
    }
  }
}

// ---------------------------------------------------------------- launcher
extern "C" void kernel_launch(void* const* d_in, const int* in_sizes, int n_in,
                              void* d_out, int out_size, void* d_ws, size_t ws_size,
                              hipStream_t stream)
{
  const float* x     = (const float*)d_in[0];
  const float* w_ih0 = (const float*)d_in[1];
  const float* w_hh0 = (const float*)d_in[2];
  const float* b_ih0 = (const float*)d_in[3];
  const float* b_hh0 = (const float*)d_in[4];
  const float* w_ih1 = (const float*)d_in[5];
  const float* w_hh1 = (const float*)d_in[6];
  const float* b_ih1 = (const float*)d_in[7];
  const float* b_hh1 = (const float*)d_in[8];
  const float* fc_w  = (const float*)d_in[9];
  const float* fc_b  = (const float*)d_in[10];
  float* out = (float*)d_out;

  char* p = (char*)d_ws;
  auto alloc = [&](size_t n) { char* r = p; p += (n + 255) & ~(size_t)255; return r; };

  u16*  xb     = (u16*)alloc((size_t)T_ * B_ * 512 * 2);
  u16*  wih0b  = (u16*)alloc((size_t)2048 * 512 * 2);
  u16*  whh0b  = (u16*)alloc((size_t)2048 * 512 * 2);
  u16*  w1b    = (u16*)alloc((size_t)2048 * 1024 * 2);
  u16*  fcwb   = (u16*)alloc((size_t)NDP * 512 * 2);
  float* bias0p = (float*)alloc(2048 * 4);
  float* bias1p = (float*)alloc(2048 * 4);
  float* fcbp   = (float*)alloc((size_t)NDP * 4);
  u16*  xg0    = (u16*)alloc((size_t)T_ * B_ * G_ * 2);
  u16*  hp0    = (u16*)alloc((size_t)2 * B_ * H_ * 2);
  u16*  hp1    = (u16*)alloc((size_t)2 * B_ * H_ * 2);
  float* raw    = (float*)alloc((size_t)B_ * NDP * 4);
  u16*  Gbuf   = (u16*)alloc((size_t)256 * 512 * 32 * 2);
  u16*  Ldbuf  = (u16*)alloc((size_t)256 * 512 * 32 * 2);
  float* idio   = (float*)alloc((size_t)256 * 512 * 4);
  unsigned* bars0 = (unsigned*)alloc(16 * 32 * 4);

  hipMemsetAsync(hp0, 0, (size_t)2 * B_ * H_ * 2, stream);
  hipMemsetAsync(hp1, 0, (size_t)2 * B_ * H_ * 2, stream);
  hipMemsetAsync(bars0, 0, 16 * 32 * 4, stream);

  dim3 blk(256);
  prep_weights_kernel<<<512, blk, 0, stream>>>(w_ih0, w_hh0, b_ih0, b_hh0,
                                               w_ih1, w_hh1, b_ih1, b_hh1,
                                               fc_w, fc_b,
                                               wih0b, whh0b, w1b, fcwb,
                                               bias0p, bias1p, fcbp);
  prep_x_kernel<<<1024, blk, 0, stream>>>(x, xb);

  // xg0 = xb @ wih0b^T + (b_ih0 + b_hh0)   [16384 x 2048 x 512]
  gemm_bt<1><<<dim3(G_ / 128, (T_ * B_) / 128), blk, 0, stream>>>(
      xb, wih0b, bias0p, xg0, T_ * B_, G_, 512);

  // fused two-layer LSTM; final h1(63) lands in hp1 slot 1
  lstm_fused_kernel<<<256, dim3(512), 0, stream>>>(xg0, whh0b, w1b, bias1p, hp0, hp1, bars0);

  // raw = h1_final @ fcwb^T + fc_b  [256 x 16640 x 512]
  gemm_bt<0><<<dim3(NDP / 128, B_ / 128), blk, 0, stream>>>(
      hp1 + (size_t)B_ * H_, fcwb, fcbp, raw, B_, NDP, 512);

  prep_sigma_kernel<<<1024, blk, 0, stream>>>(raw, Gbuf, Ldbuf, idio);
  sigma_kernel<<<dim3(4, 4, 256), blk, 0, stream>>>(Gbuf, Ldbuf, idio, out);
}